// Round 4
// baseline (331.369 us; speedup 1.0000x reference)
//
#include <hip/hip_runtime.h>

#define NN 50000
#define NE 400000
#define NPB 32                      // nodes per edge-block
#define NB ((NN + NPB - 1) / NPB)   // 1563
#define SCAP 32                     // per-node out-edge capacity (max deg ~27)
#define DCAP 32                     // per-node in-edge capacity
#define YSTRIDE 276                 // 272 + pad; 276 mod 32 = 20 -> 8-node reads conflict-free

// ws layout (bytes):
//   msg1  float [NN*DCAP*16]  102.4 MB
//   msg2  float [NN*DCAP*16]  102.4 MB
//   h1    float [16*NN]         3.2 MB
//   cur_src int [NN]          200 KB (zeroed)
//   cur_dst int [NN]          200 KB (zeroed)
//   ord   int2  [NN*SCAP]      12.8 MB  {eid, (d<<5)+sd}

// ---------------------------------------------------------------------------
__global__ __launch_bounds__(256) void fill_kernel(
    const int* __restrict__ eidx, int* __restrict__ cur_src,
    int* __restrict__ cur_dst, int2* __restrict__ ord)
{
    int e = blockIdx.x * 256 + threadIdx.x;
    if (e < NE) {
        int s = eidx[e], d = eidx[NE + e];
        int ss = atomicAdd(&cur_src[s], 1);
        int sd = atomicAdd(&cur_dst[d], 1);
        if (ss < SCAP && sd < DCAP)   // statistically impossible to overflow
            ord[((size_t)s << 5) + ss] = make_int2(e, (d << 5) + sd);
    }
}

// ---------------------------------------------------------------------------
// Per-edge message: hid = relu(ea@w1+b1); msg = Y0 + sum_k hid[k]*Y[k];
// float4 stores to mout[pd]. Yn points at this src node's Y slice in LDS.
// ---------------------------------------------------------------------------
__device__ __forceinline__ void edge_compute(
    float4 a0, float4 a1,
    const float* __restrict__ w1, const float* __restrict__ b1,
    const float* __restrict__ Yn, float* __restrict__ mout, int pd)
{
    float a[8] = {a0.x, a0.y, a0.z, a0.w, a1.x, a1.y, a1.z, a1.w};
    float hid[16];
#pragma unroll
    for (int jj = 0; jj < 16; ++jj) hid[jj] = b1[jj];
#pragma unroll
    for (int c = 0; c < 8; ++c)
#pragma unroll
        for (int jj = 0; jj < 16; ++jj) hid[jj] += a[c] * w1[c * 16 + jj];
#pragma unroll
    for (int jj = 0; jj < 16; ++jj) hid[jj] = fmaxf(hid[jj], 0.0f);

    const float4* Yr = (const float4*)Yn;
    float4 m0 = Yr[64], m1 = Yr[65], m2 = Yr[66], m3 = Yr[67];  // Y0 (b2 term)
#pragma unroll
    for (int k = 0; k < 16; ++k) {
        float hk = hid[k];
        float4 y0 = Yr[k * 4 + 0], y1 = Yr[k * 4 + 1];
        float4 y2 = Yr[k * 4 + 2], y3 = Yr[k * 4 + 3];
        m0.x = fmaf(hk, y0.x, m0.x); m0.y = fmaf(hk, y0.y, m0.y);
        m0.z = fmaf(hk, y0.z, m0.z); m0.w = fmaf(hk, y0.w, m0.w);
        m1.x = fmaf(hk, y1.x, m1.x); m1.y = fmaf(hk, y1.y, m1.y);
        m1.z = fmaf(hk, y1.z, m1.z); m1.w = fmaf(hk, y1.w, m1.w);
        m2.x = fmaf(hk, y2.x, m2.x); m2.y = fmaf(hk, y2.y, m2.y);
        m2.z = fmaf(hk, y2.z, m2.z); m2.w = fmaf(hk, y2.w, m2.w);
        m3.x = fmaf(hk, y3.x, m3.x); m3.y = fmaf(hk, y3.y, m3.y);
        m3.z = fmaf(hk, y3.z, m3.z); m3.w = fmaf(hk, y3.w, m3.w);
    }
    float4* mp = (float4*)(mout + (size_t)pd * 16);
    mp[0] = m0; mp[1] = m1; mp[2] = m2; mp[3] = m3;
}

// ---------------------------------------------------------------------------
// Edge kernel. Block = NPB consecutive src nodes.
// SECOND=true: staging fuses the layer-1 node update (h1) for the block's
//              own nodes.
// Phase 2 thread map: (node = tid>>3, slot = tid&7); ord+ea prefetched so
// their latency hides under phase-1 Y computation.
// ---------------------------------------------------------------------------
template <bool SECOND>
__global__ __launch_bounds__(256) void edge_fused_kernel(
    const float* __restrict__ xin,     // x [N,16]
    const float* __restrict__ min_,    // SECOND: msg1
    const int*   __restrict__ cur_dst, // SECOND: in-degree
    const float* __restrict__ rootp,   // SECOND: root1
    const float* __restrict__ biasp,   // SECOND: bias1
    float*       __restrict__ h1_out,  // SECOND: h1 written here
    const float* __restrict__ ea,      // [E,8]
    const int2*  __restrict__ ord,     // [NN*SCAP]
    const int*   __restrict__ cur_src, // [NN]
    const float* __restrict__ w1,      // [8,16]
    const float* __restrict__ b1,      // [16]
    const float* __restrict__ w2,      // [16,256]
    const float* __restrict__ b2,      // [256]
    float*       __restrict__ mout)    // [NN*DCAP,16]
{
    __shared__ float xl[NPB * 16];
    __shared__ float Yl[NPB * YSTRIDE];

    int tid = threadIdx.x;
    int n0 = blockIdx.x * NPB;
    int o = tid & 15;

    // ---- phase-2 prefetch part 1: count + ord (independent of staging)
    int pnode = tid >> 3;        // 0..31
    int pslot = tid & 7;
    int pn = n0 + pnode;
    int pcnt = 0;
    if (pn < NN) { int c = cur_src[pn]; pcnt = c < SCAP ? c : SCAP; }
    bool v0 = pslot < pcnt;
    int pe = 0, ppd = 0;
    if (v0) { int2 od = ord[((size_t)pn << 5) + pslot]; pe = od.x; ppd = od.y; }

    // ---- staging: 2 nodes per thread (layer2: fused layer-1 node update)
#pragma unroll
    for (int rep = 0; rep < 2; ++rep) {
        int node = (tid >> 4) + rep * 16;
        int n = n0 + node;
        float val = 0.0f;
        if (n < NN) {
            if (!SECOND) {
                val = xin[(size_t)n * 16 + o];
            } else {
                int craw = cur_dst[n];
                int cnt = craw < DCAP ? craw : DCAP;
                const float* mp = min_ + ((size_t)n << 5) * 16;
                float s0 = 0, s1 = 0, s2 = 0, s3 = 0;
                int j = 0;
                for (; j + 4 <= cnt; j += 4) {
                    s0 += mp[(j + 0) * 16 + o]; s1 += mp[(j + 1) * 16 + o];
                    s2 += mp[(j + 2) * 16 + o]; s3 += mp[(j + 3) * 16 + o];
                }
                for (; j < cnt; ++j) s0 += mp[j * 16 + o];
                float sum = (s0 + s1) + (s2 + s3);
                float acc = sum / (float)(craw > 0 ? craw : 1) + biasp[o];
                float xo = xin[(size_t)n * 16 + o];
#pragma unroll
                for (int i = 0; i < 16; ++i)
                    acc += __shfl(xo, i, 16) * rootp[i * 16 + o];
                val = fmaxf(acc, 0.0f);
                h1_out[(size_t)n * 16 + o] = val;
            }
        }
        xl[node * 16 + o] = val;
    }
    __syncthreads();

    // ---- phase-2 prefetch part 2: ea (latency hides under phase 1 below)
    float4 a0 = make_float4(0, 0, 0, 0), a1 = make_float4(0, 0, 0, 0);
    if (v0) {
        const float4* av = (const float4*)(ea + (size_t)pe * 8);
        a0 = av[0]; a1 = av[1];
    }

    // ---- phase 1a: Y slices k=0..15; thread (k,o) keeps 16 weights in regs
    {
        int k = tid >> 4;
        float w[16];
#pragma unroll
        for (int i = 0; i < 16; ++i) w[i] = w2[k * 256 + i * 16 + o];
#pragma unroll 4
        for (int nd = 0; nd < NPB; ++nd) {
            const float4* xr = (const float4*)&xl[nd * 16];
            float4 x0 = xr[0], x1 = xr[1], x2 = xr[2], x3 = xr[3];
            float acc = x0.x * w[0] + x0.y * w[1] + x0.z * w[2] + x0.w * w[3]
                      + x1.x * w[4] + x1.y * w[5] + x1.z * w[6] + x1.w * w[7]
                      + x2.x * w[8] + x2.y * w[9] + x2.z * w[10] + x2.w * w[11]
                      + x3.x * w[12] + x3.y * w[13] + x3.z * w[14] + x3.w * w[15];
            Yl[nd * YSTRIDE + k * 16 + o] = acc;
        }
    }
    // ---- phase 1b: Y0 slice (b2); 2 nodes per thread
#pragma unroll
    for (int rep = 0; rep < 2; ++rep) {
        int node = (tid >> 4) + rep * 16;
        float w[16];
#pragma unroll
        for (int i = 0; i < 16; ++i) w[i] = b2[i * 16 + o];
        const float4* xr = (const float4*)&xl[node * 16];
        float4 x0 = xr[0], x1 = xr[1], x2 = xr[2], x3 = xr[3];
        float acc = x0.x * w[0] + x0.y * w[1] + x0.z * w[2] + x0.w * w[3]
                  + x1.x * w[4] + x1.y * w[5] + x1.z * w[6] + x1.w * w[7]
                  + x2.x * w[8] + x2.y * w[9] + x2.z * w[10] + x2.w * w[11]
                  + x3.x * w[12] + x3.y * w[13] + x3.z * w[14] + x3.w * w[15];
        Yl[node * YSTRIDE + 256 + o] = acc;
    }
    __syncthreads();

    // ---- phase 2: consume prefetched edge, then tail slots (>=8)
    const float* Yn = &Yl[pnode * YSTRIDE];
    if (v0) edge_compute(a0, a1, w1, b1, Yn, mout, ppd);
    for (int slot = pslot + 8; slot < pcnt; slot += 8) {
        int2 od = ord[((size_t)pn << 5) + slot];
        const float4* av = (const float4*)(ea + (size_t)od.x * 8);
        float4 b0 = av[0], b1v = av[1];
        edge_compute(b0, b1v, w1, b1, Yn, mout, od.y);
    }
}

// ---------------------------------------------------------------------------
// Final node kernel: mean over own msg2 range, layer-2 update + q head.
// ---------------------------------------------------------------------------
__global__ __launch_bounds__(256) void node2q_kernel(
    const float* __restrict__ h1, const float* __restrict__ msg2,
    const int* __restrict__ cur_dst,
    const float* __restrict__ root, const float* __restrict__ bias,
    const float* __restrict__ qw, const float* __restrict__ qb,
    float* __restrict__ out)
{
    int t = blockIdx.x * 256 + threadIdx.x;
    int n = t >> 4, o = t & 15;
    if (n >= NN) return;

    int craw = cur_dst[n];
    int cnt = craw < DCAP ? craw : DCAP;
    const float* mp = msg2 + ((size_t)n << 5) * 16;
    float s0 = 0, s1 = 0, s2 = 0, s3 = 0;
    int j = 0;
    for (; j + 4 <= cnt; j += 4) {
        s0 += mp[(j + 0) * 16 + o]; s1 += mp[(j + 1) * 16 + o];
        s2 += mp[(j + 2) * 16 + o]; s3 += mp[(j + 3) * 16 + o];
    }
    for (; j < cnt; ++j) s0 += mp[j * 16 + o];
    float acc = ((s0 + s1) + (s2 + s3)) / (float)(craw > 0 ? craw : 1) + bias[o];

    float ho = h1[(size_t)n * 16 + o];
#pragma unroll
    for (int i = 0; i < 16; ++i)
        acc += __shfl(ho, i, 16) * root[i * 16 + o];

    float q = fmaxf(acc, 0.0f) * qw[o];
#pragma unroll
    for (int d = 8; d >= 1; d >>= 1) q += __shfl_down(q, d, 16);
    if (o == 0) out[n] = q + qb[0];
}

extern "C" void kernel_launch(void* const* d_in, const int* in_sizes, int n_in,
                              void* d_out, int out_size, void* d_ws, size_t ws_size,
                              hipStream_t stream) {
    const float* x     = (const float*)d_in[0];
    const float* ea    = (const float*)d_in[1];
    const float* e1w1  = (const float*)d_in[2];
    const float* e1b1  = (const float*)d_in[3];
    const float* e1w2  = (const float*)d_in[4];
    const float* e1b2  = (const float*)d_in[5];
    const float* root1 = (const float*)d_in[6];
    const float* bias1 = (const float*)d_in[7];
    const float* e2w1  = (const float*)d_in[8];
    const float* e2b1  = (const float*)d_in[9];
    const float* e2w2  = (const float*)d_in[10];
    const float* e2b2  = (const float*)d_in[11];
    const float* root2 = (const float*)d_in[12];
    const float* bias2 = (const float*)d_in[13];
    const float* qw    = (const float*)d_in[14];
    const float* qb    = (const float*)d_in[15];
    const int*   eidx  = (const int*)d_in[16];

    float* msg1    = (float*)d_ws;                          // NN*DCAP*16
    float* msg2    = msg1 + (size_t)NN * DCAP * 16;         // NN*DCAP*16
    float* h1      = msg2 + (size_t)NN * DCAP * 16;         // 16*NN
    int*   cur_src = (int*)(h1 + (size_t)16 * NN);          // NN (zeroed)
    int*   cur_dst = cur_src + NN;                          // NN (zeroed)
    int2*  ord     = (int2*)(cur_dst + NN);                 // NN*SCAP

    int eblocks = (NE + 255) / 256;  // 1563

    hipMemsetAsync(cur_src, 0, (size_t)2 * NN * sizeof(int), stream);

    fill_kernel<<<eblocks, 256, 0, stream>>>(eidx, cur_src, cur_dst, ord);

    // layer 1 edges
    edge_fused_kernel<false><<<NB, 256, 0, stream>>>(
        x, nullptr, nullptr, nullptr, nullptr, nullptr,
        ea, ord, cur_src, e1w1, e1b1, e1w2, e1b2, msg1);

    // layer 2 edges (+ fused layer-1 node update -> h1)
    edge_fused_kernel<true><<<NB, 256, 0, stream>>>(
        x, msg1, cur_dst, root1, bias1, h1,
        ea, ord, cur_src, e2w1, e2b1, e2w2, e2b2, msg2);

    // layer-2 node update + q head
    node2q_kernel<<<3125, 256, 0, stream>>>(
        h1, msg2, cur_dst, root2, bias2, qw, qb, (float*)d_out);
}